// Round 7
// baseline (79.887 us; speedup 1.0000x reference)
//
#include <hip/hip_runtime.h>

// ColorDenseCRFLoss via 32x32x16 MFMA + triangle symmetry + LDS-staged B:
// out = -1e-7/4 * sum_{n,p,q} exp(-0.5*||f_p-f_q||^2) * (seg_p . seg_q)
// Tiles of 32 pixels; pair (i<j) weight 2, diagonal tile weight 1 (whole
// tile counted once covers (p,q)+(q,p)). Block-pair bp owns strips bp and
// 31-bp (4 tiles each); j streams [first,128) => 132 steps/block-pair,
// split 16 ways. B-tiles staged in LDS via global_load_lds, double-buffered.

#define N_BATCH 4
#define IH 128
#define IW 128
#define P 4096   // 64x64 downsampled pixels per batch
#define KC 21

using short8   = __attribute__((ext_vector_type(8))) short;
using floatx16 = __attribute__((ext_vector_type(16))) float;

static constexpr float INV_SIGMA = 1.0f / 15.0f;
static constexpr float LOG2E     = 1.4426950408889634f;
static constexpr float OUT_SCALE = -1e-7f / 4.0f;

// ws layout: argA/argB rows 32B (16 bf16, K=16); seg lo/hi planes rows 32B
// (k 0..15 and 16..31, zeros past 21). All B-tiles = contiguous 1KB chunks.
#define ARGA_OFF  0
#define ARGB_OFF  (N_BATCH * P * 32)
#define SEGLO_OFF (2 * N_BATCH * P * 32)
#define SEGHI_OFF (3 * N_BATCH * P * 32)

#define NFEAT (N_BATCH * P)              // 16384
#define NSEG2 (N_BATCH * KC * P / 2)     // 172032 (2 pixels/thread)

__device__ __forceinline__ ushort f2bf(float x) {  // RNE float->bf16 bits
    unsigned u = __builtin_bit_cast(unsigned, x);
    unsigned r = (u + 0x7FFFu + ((u >> 16) & 1u)) >> 16;
    return (ushort)r;
}
__device__ __forceinline__ float bf2f(ushort h) {
    return __builtin_bit_cast(float, (unsigned)h << 16);
}

__device__ __forceinline__ void gload16(const void* g, void* l) {
    __builtin_amdgcn_global_load_lds(
        (const __attribute__((address_space(1))) unsigned int*)g,
        (__attribute__((address_space(3))) unsigned int*)l, 16, 0, 0);
}

__global__ void crf_prep(const float* __restrict__ img,
                         const float* __restrict__ seg,
                         char* __restrict__ wsb,
                         float* __restrict__ out)
{
    int t = blockIdx.x * blockDim.x + threadIdx.x;
    if (t < NFEAT) {
        if (t == 0) out[0] = 0.0f;

        int n = t >> 12;
        int p = t & (P - 1);
        int y = p >> 6, x = p & 63;

        const float* ib = img + (size_t)n * 3 * IH * IW + (size_t)(2 * y) * IW + 2 * x;
        float f0 = ib[0] * INV_SIGMA;
        float f1 = ib[IH * IW] * INV_SIGMA;
        float f2 = ib[2 * IH * IW] * INV_SIGMA;
        float h = 0.5f * (f0 * f0 + f1 * f1 + f2 * f2);

        float fa0 = f0 * LOG2E, fa1 = f1 * LOG2E, fa2 = f2 * LOG2E;
        ushort ah0 = f2bf(fa0), ah1 = f2bf(fa1), ah2 = f2bf(fa2);
        ushort al0 = f2bf(fa0 - bf2f(ah0));
        ushort al1 = f2bf(fa1 - bf2f(ah1));
        ushort al2 = f2bf(fa2 - bf2f(ah2));
        float nhL = -h * LOG2E;
        ushort nhh = f2bf(nhL), nhl = f2bf(nhL - bf2f(nhh));
        ushort bh0 = f2bf(f0), bh1 = f2bf(f1), bh2 = f2bf(f2);
        ushort bl0 = f2bf(f0 - bf2f(bh0));
        ushort bl1 = f2bf(f1 - bf2f(bh1));
        ushort bl2 = f2bf(f2 - bf2f(bh2));
        float hL = h * LOG2E;
        ushort hbh = f2bf(hL), hbl = f2bf(hL - bf2f(hbh));

        const ushort ONE = 0x3F80, NEG1 = 0xBF80;
        // dot(argA_p, argB_q) = log2e * (f_p.f_q - h_p - h_q)
        ushort rA[16] = {ah0, ah1, ah2, ah0, ah1, ah2, al0, al1, al2, al0, al1, al2,
                         nhh, nhl, NEG1, NEG1};
        ushort rB[16] = {bh0, bh1, bh2, bl0, bl1, bl2, bh0, bh1, bh2, bl0, bl1, bl2,
                         ONE, ONE, hbh, hbl};

        short8 vA0, vA1, vB0, vB1;
#pragma unroll
        for (int j = 0; j < 8; ++j) {
            vA0[j] = (short)rA[j];     vA1[j] = (short)rA[8 + j];
            vB0[j] = (short)rB[j];     vB1[j] = (short)rB[8 + j];
        }
        short8* dA = (short8*)(wsb + ARGA_OFF + (size_t)t * 32);
        dA[0] = vA0; dA[1] = vA1;
        short8* dB = (short8*)(wsb + ARGB_OFF + (size_t)t * 32);
        dB[0] = vB0; dB[1] = vB1;

        // zero seg-hi plane tail (k' = 5..15 -> bytes 10..31)
        char* hp = wsb + SEGHI_OFF + (size_t)t * 32;
        *(ushort*)(hp + 10) = 0;
        *(uint*)(hp + 12) = 0;
        *(size_t*)(hp + 16) = 0;
        *(size_t*)(hp + 24) = 0;
    } else if (t < NFEAT + NSEG2) {
        int u = t - NFEAT;
        int pp = (u & 2047) * 2;     // pixel pair base (even)
        int nk = u >> 11;            // n*21 + k
        int n = nk / 21;
        int k = nk - n * 21;
        int y = pp >> 6, x0 = pp & 63;

        const float* r0 = seg + (size_t)nk * IH * IW + (size_t)(2 * y) * IW + 2 * x0;
        float4 a = *(const float4*)r0;
        float4 b = *(const float4*)(r0 + IW);
        float v0 = 0.25f * ((a.x + a.y) + (b.x + b.y));
        float v1 = 0.25f * ((a.z + a.w) + (b.z + b.w));
        size_t off = (k < 16) ? (SEGLO_OFF + (size_t)(n * P + pp) * 32 + k * 2)
                              : (SEGHI_OFF + (size_t)(n * P + pp) * 32 + (k - 16) * 2);
        char* d = wsb + off;
        *(ushort*)d = f2bf(v0);
        *(ushort*)(d + 32) = f2bf(v1);
    }
}

__device__ __forceinline__ void tilestep(short8 aA, short8 aL, short8 aH,
                                         short8 bA, short8 bL, short8 bH,
                                         float& acc)
{
    floatx16 z = {0.0f};
    floatx16 g  = __builtin_amdgcn_mfma_f32_32x32x16_bf16(aL, bL, z, 0, 0, 0);
    g           = __builtin_amdgcn_mfma_f32_32x32x16_bf16(aH, bH, g, 0, 0, 0);
    floatx16 ar = __builtin_amdgcn_mfma_f32_32x32x16_bf16(aA, bA, z, 0, 0, 0);
    float s = 0.0f;
#pragma unroll
    for (int r = 0; r < 16; ++r)
        s += __builtin_amdgcn_exp2f(ar[r]) * g[r];
    acc += s;
}

__global__ __launch_bounds__(256, 4) void crf_pair(const char* __restrict__ wsb,
                                                   float* __restrict__ out)
{
    int n = blockIdx.z;
    int bp = blockIdx.y;             // [0,16): strips bp and 31-bp
    int bx = blockIdx.x;             // [0,16): j-step split, stride 16
    int wave = threadIdx.x >> 6;
    int lane = threadIdx.x & 63;
    int m31 = lane & 31;
    int hi  = lane >> 5;

    const char* argA = wsb + ARGA_OFF  + (size_t)n * P * 32;
    const char* argB = wsb + ARGB_OFF  + (size_t)n * P * 32;
    const char* segL = wsb + SEGLO_OFF + (size_t)n * P * 32;
    const char* segH = wsb + SEGHI_OFF + (size_t)n * P * 32;

    int cnt0 = 128 - 4 * bp;         // phase0 step count (total 132)
    int i0t = 4 * bp + wave;         // this wave's strip0 i-tile
    int i1t = 124 - 4 * bp + wave;   // this wave's strip1 i-tile
    int rd = m31 * 32 + hi * 16;     // per-lane frag offset within a 1KB tile

    // A fragments: direct global loads, once
    short8 aA0 = *(const short8*)(argA + (size_t)i0t * 1024 + rd);
    short8 aL0 = *(const short8*)(segL + (size_t)i0t * 1024 + rd);
    short8 aH0 = *(const short8*)(segH + (size_t)i0t * 1024 + rd);
    short8 aA1 = *(const short8*)(argA + (size_t)i1t * 1024 + rd);
    short8 aL1 = *(const short8*)(segL + (size_t)i1t * 1024 + rd);
    short8 aH1 = *(const short8*)(segH + (size_t)i1t * 1024 + rd);

    __shared__ __align__(16) char lbuf[2 * 3072];   // double buffer: 1K arg + 1K segLo + 1K segHi
    __shared__ float wsum[4];

    int nst = (bx < 4) ? 9 : 8;      // steps m = bx + 16*t < 132

    // prologue: stage step 0 into buf 0 (waves 0..2, one 1KB chunk each)
    {
        int m = bx;
        int j = (m < cnt0) ? (4 * bp + m) : (m - 4);
        if (wave == 0)      gload16(argB + (size_t)j * 1024 + lane * 16, lbuf);
        else if (wave == 1) gload16(segL + (size_t)j * 1024 + lane * 16, lbuf + 1024);
        else if (wave == 2) gload16(segH + (size_t)j * 1024 + lane * 16, lbuf + 2048);
    }
    __syncthreads();

    float acc1 = 0.0f, acc2 = 0.0f;
    for (int t = 0; t < nst; ++t) {
        int cur = (t & 1) * 3072;
        if (t + 1 < nst) {           // prefetch next step into other buffer
            int mn = bx + 16 * (t + 1);
            int jn = (mn < cnt0) ? (4 * bp + mn) : (mn - 4);
            int nxt = 3072 - cur;
            if (wave == 0)      gload16(argB + (size_t)jn * 1024 + lane * 16, lbuf + nxt);
            else if (wave == 1) gload16(segL + (size_t)jn * 1024 + lane * 16, lbuf + nxt + 1024);
            else if (wave == 2) gload16(segH + (size_t)jn * 1024 + lane * 16, lbuf + nxt + 2048);
        }

        int m = bx + 16 * t;
        int j = (m < cnt0) ? (4 * bp + m) : (m - 4);
        short8 bA = *(const short8*)(lbuf + cur + rd);
        short8 bL = *(const short8*)(lbuf + cur + 1024 + rd);
        short8 bH = *(const short8*)(lbuf + cur + 2048 + rd);

        if (m < cnt0) {              // strip0 (wave-uniform branches, static bodies)
            if (i0t < j)       tilestep(aA0, aL0, aH0, bA, bL, bH, acc2);
            else if (i0t == j) tilestep(aA0, aL0, aH0, bA, bL, bH, acc1);
        } else {                     // strip1
            if (i1t < j)       tilestep(aA1, aL1, aH1, bA, bL, bH, acc2);
            else if (i1t == j) tilestep(aA1, aL1, aH1, bA, bL, bH, acc1);
        }
        __syncthreads();             // drains this step's prefetch; frees cur buf
    }

    float part = 2.0f * acc2 + acc1;
#pragma unroll
    for (int off = 32; off > 0; off >>= 1)
        part += __shfl_down(part, off, 64);
    if (lane == 0) wsum[wave] = part;
    __syncthreads();
    if (threadIdx.x == 0)
        atomicAdd(out, ((wsum[0] + wsum[1]) + (wsum[2] + wsum[3])) * OUT_SCALE);
}

extern "C" void kernel_launch(void* const* d_in, const int* in_sizes, int n_in,
                              void* d_out, int out_size, void* d_ws, size_t ws_size,
                              hipStream_t stream)
{
    const float* images = (const float*)d_in[0];   // [4,3,128,128]
    const float* segm   = (const float*)d_in[1];   // [4,21,128,128]
    float* out = (float*)d_out;                    // [1]
    char* wsb = (char*)d_ws;                       // 2 MB used

    int prep_threads = NFEAT + NSEG2;
    crf_prep<<<dim3((prep_threads + 255) / 256), dim3(256), 0, stream>>>(
        images, segm, wsb, out);
    crf_pair<<<dim3(16, 16, N_BATCH), dim3(256), 0, stream>>>(wsb, out);
}